// Round 6
// baseline (137.550 us; speedup 1.0000x reference)
//
#include <hip/hip_runtime.h>
#include <hip/hip_fp16.h>

#define T    65536
#define TOUT 65532
#define NB   16
#define CH   32
#define NF   32
#define KS   5
#define BM   128
#define NCHB 2048          // chsum grid

typedef _Float16 f16x8 __attribute__((ext_vector_type(8)));
typedef _Float16 f16x4 __attribute__((ext_vector_type(4)));
typedef float    f32x4 __attribute__((ext_vector_type(4)));

// ws: ws[0..31] = per-channel sums; ws[32] = scalar s; ((uint*)ws)[40] = arrival counter

__device__ __forceinline__ f16x4 cvt4(float4 v) {
    f16x4 h;
    h[0] = (_Float16)v.x; h[1] = (_Float16)v.y;
    h[2] = (_Float16)v.z; h[3] = (_Float16)v.w;
    return h;
}

// ---- Kernel 1: per-channel sums; LAST block computes s inline (no serial kernel) ----
__global__ __launch_bounds__(256) void chsum2_kernel(const float* __restrict__ x,
                                                     const float* __restrict__ Wconv,
                                                     const float* __restrict__ bconv,
                                                     const float* __restrict__ Wdef,
                                                     float* __restrict__ ws) {
    __shared__ float tot[CH];
    __shared__ float hb[4][CH], tb[4][CH];
    __shared__ float partial[256];
    __shared__ int   lastflag;

    const int tid = threadIdx.x;
    if (tid < CH) tot[tid] = 0.f;
    __syncthreads();

    // grid-stride per-channel sums (proven round-1 pattern)
    {
        size_t idx4   = (size_t)blockIdx.x * blockDim.x + tid;
        size_t n4     = (size_t)NB * T * CH / 4;
        size_t stride = (size_t)NCHB * 256;          // *4 floats % 32 == 0
        int c0 = (int)((idx4 * 4) & (CH - 1));       // invariant across iters
        float s0 = 0.f, s1 = 0.f, s2 = 0.f, s3 = 0.f;
        const float4* x4 = (const float4*)x;
        for (size_t i = idx4; i < n4; i += stride) {
            float4 v = x4[i];
            s0 += v.x; s1 += v.y; s2 += v.z; s3 += v.w;
        }
        atomicAdd(&tot[c0 + 0], s0);
        atomicAdd(&tot[c0 + 1], s1);
        atomicAdd(&tot[c0 + 2], s2);
        atomicAdd(&tot[c0 + 3], s3);
    }
    __syncthreads();
    if (tid < CH) {
        // device-scope release add: pairs with last block's acq_rel counter bump
        float old = __hip_atomic_fetch_add(&ws[tid], tot[tid],
                                           __ATOMIC_RELEASE, __HIP_MEMORY_SCOPE_AGENT);
        asm volatile("" :: "v"(old));
    }
    __syncthreads();

    if (tid == 0) {
        unsigned int* cnt = (unsigned int*)ws + 40;
        unsigned int old = __hip_atomic_fetch_add(cnt, 1u, __ATOMIC_ACQ_REL,
                                                  __HIP_MEMORY_SCOPE_AGENT);
        lastflag = (old == (unsigned)(NCHB - 1));
    }
    __syncthreads();
    if (!lastflag) return;

    // ---- last block: compute s with full 256-thread parallelism ----
    {
        int j = tid >> 5, c = tid & 31;              // j in 0..7
        int row = (j < 4) ? j : (T - 8 + j);
        float e = 0.f;
        for (int bb = 0; bb < NB; ++bb)
            e += x[((size_t)bb * T + row) * CH + c]; // 16 independent L3-hot loads
        if (j < 4) hb[j][c] = e; else tb[j - 4][c] = e;
    }
    __syncthreads();
    float term = 0.f;
    if (tid < KS * CH) {
        int k = tid >> 5, c = tid & 31;
        float wf = 0.f;
        const float* wp = &Wconv[(size_t)tid * NF];
        for (int f = 0; f < NF; ++f) wf += wp[f];
        float S = __hip_atomic_load(&ws[c], __ATOMIC_RELAXED, __HIP_MEMORY_SCOPE_AGENT);
        for (int jj = 0; jj < k; ++jj) S -= hb[jj][c];
        for (int jj = k; jj < 4; ++jj) S -= tb[jj][c];
        term = wf * S;
    }
    partial[tid] = term;
    __syncthreads();
    for (int off = 128; off > 0; off >>= 1) {
        if (tid < off) partial[tid] += partial[tid + off];
        __syncthreads();
    }
    if (tid == 0) {
        float sum_b = 0.f;
        for (int f = 0; f < NF; ++f) sum_b += bconv[f];
        float mean_off = partial[0] / (float)((size_t)NB * TOUT * NF) + sum_b / (float)NF;
        float s = 0.f;
        for (int k = 0; k < KS; ++k) {
            float pn = mean_off + (float)(k - 2);
            s += Wdef[k] * fmaxf(0.f, 1.f - fabsf(pn));
        }
        __hip_atomic_store(&ws[CH], s, __ATOMIC_RELEASE, __HIP_MEMORY_SCOPE_AGENT);
    }
}

// ---- Kernel 2: conv via f16 MFMA (round-1 proven, unchanged) ----
__global__ __launch_bounds__(256) void conv_kernel(const float* __restrict__ x,
                                                   const float* __restrict__ Wconv,
                                                   const float* __restrict__ bconv,
                                                   const float* __restrict__ ws,
                                                   float* __restrict__ out) {
    __shared__ _Float16 A[(BM + 4) * 40];
    __shared__ _Float16 Wt[KS * CH * 40];

    int tid = threadIdx.x;
    int b   = blockIdx.y;
    int t0  = blockIdx.x * BM;

    const int AROWS = BM + 4;
    {
        int c0 = (tid & 7) * 4;
        for (int r = (tid >> 3); r < AROWS; r += 32) {
            int t = t0 + r;
            float4 v = make_float4(0.f, 0.f, 0.f, 0.f);
            if (t < T) v = *(const float4*)&x[((size_t)b * T + t) * CH + c0];
            *(f16x4*)&A[r * 40 + c0] = cvt4(v);
        }
    }
    if (tid < KS * CH) {
        int k = tid >> 5, c = tid & 31;
        const float* wp = &Wconv[(size_t)tid * NF];
        for (int f = 0; f < NF; ++f)
            Wt[(k * CH + f) * 40 + c] = (_Float16)wp[f];
    }
    __syncthreads();

    int lane = tid & 63;
    int wave = tid >> 6;
    int rowbase = wave * 32;
    int lrow = lane & 15;
    int kgrp = lane >> 4;

    f32x4 acc00 = {}, acc01 = {}, acc10 = {}, acc11 = {};
#pragma unroll
    for (int kk = 0; kk < KS; ++kk) {
        f16x8 a0 = *(const f16x8*)&A[(rowbase + lrow + kk) * 40 + kgrp * 8];
        f16x8 a1 = *(const f16x8*)&A[(rowbase + 16 + lrow + kk) * 40 + kgrp * 8];
        f16x8 b0 = *(const f16x8*)&Wt[(kk * CH + lrow) * 40 + kgrp * 8];
        f16x8 b1 = *(const f16x8*)&Wt[(kk * CH + 16 + lrow) * 40 + kgrp * 8];
        acc00 = __builtin_amdgcn_mfma_f32_16x16x32_f16(a0, b0, acc00, 0, 0, 0);
        acc01 = __builtin_amdgcn_mfma_f32_16x16x32_f16(a0, b1, acc01, 0, 0, 0);
        acc10 = __builtin_amdgcn_mfma_f32_16x16x32_f16(a1, b0, acc10, 0, 0, 0);
        acc11 = __builtin_amdgcn_mfma_f32_16x16x32_f16(a1, b1, acc11, 0, 0, 0);
    }

    float sv  = ws[CH];
    int col0  = lane & 15;
    float bc0 = bconv[col0], bc1 = bconv[col0 + 16];
    int rbase = rowbase + ((lane >> 4) << 2);
#pragma unroll
    for (int reg = 0; reg < 4; ++reg) {
        int t = t0 + rbase + reg;
        if (t < TOUT) {
            float* o = &out[((size_t)b * TOUT + t) * NF];
            o[col0]      = sv * acc00[reg] + bc0;
            o[col0 + 16] = sv * acc01[reg] + bc1;
        }
        int t1 = t + 16;
        if (t1 < TOUT) {
            float* o = &out[((size_t)b * TOUT + t1) * NF];
            o[col0]      = sv * acc10[reg] + bc0;
            o[col0 + 16] = sv * acc11[reg] + bc1;
        }
    }
}

extern "C" void kernel_launch(void* const* d_in, const int* in_sizes, int n_in,
                              void* d_out, int out_size, void* d_ws, size_t ws_size,
                              hipStream_t stream) {
    const float* x     = (const float*)d_in[0];
    const float* Wconv = (const float*)d_in[1];
    const float* bconv = (const float*)d_in[2];
    const float* Wdef  = (const float*)d_in[3];
    float* out = (float*)d_out;
    float* ws  = (float*)d_ws;

    hipMemsetAsync(ws, 0, 256, stream);   // sums + counter + s zeroed every call

    chsum2_kernel<<<dim3(NCHB), dim3(256), 0, stream>>>(x, Wconv, bconv, Wdef, ws);
    dim3 grid((TOUT + BM - 1) / BM, NB);
    conv_kernel<<<grid, dim3(256), 0, stream>>>(x, Wconv, bconv, ws, out);
}

// Round 7
// 88.876 us; speedup vs baseline: 1.5477x; 1.5477x over previous
//
#include <hip/hip_runtime.h>
#include <hip/hip_fp16.h>

#define T    65536
#define TOUT 65532
#define NB   16
#define CH   32
#define NF   32
#define KS   5
#define BM   128
#define NCHB 2048          // chsum grid; 2048*256*16 float4 == NB*T*CH/4 exactly

typedef _Float16 f16x8 __attribute__((ext_vector_type(8)));
typedef _Float16 f16x4 __attribute__((ext_vector_type(4)));
typedef float    f32x4 __attribute__((ext_vector_type(4)));

// ws layout: ws[32] = scalar s; partials[2048][32] at ws+64 (byte 256).
// No global atomics anywhere; cross-kernel visibility via stream ordering.

__device__ __forceinline__ f16x4 cvt4(float4 v) {
    f16x4 h;
    h[0] = (_Float16)v.x; h[1] = (_Float16)v.y;
    h[2] = (_Float16)v.z; h[3] = (_Float16)v.w;
    return h;
}

// ---- K1: per-block per-channel partial sums, private-line plain stores ----
__global__ __launch_bounds__(256) void chsum3_kernel(const float* __restrict__ x,
                                                     float* __restrict__ partials) {
    __shared__ float tot[CH];
    const int tid = threadIdx.x;
    if (tid < CH) tot[tid] = 0.f;
    __syncthreads();

    const float4* x4 = (const float4*)x;
    const size_t idx4 = (size_t)blockIdx.x * 256 + tid;
    float s0 = 0.f, s1 = 0.f, s2 = 0.f, s3 = 0.f;
#pragma unroll
    for (int q = 0; q < 16; ++q) {                  // 16 independent streaming loads
        float4 v = x4[idx4 + (size_t)q * (NCHB * 256)];
        s0 += v.x; s1 += v.y; s2 += v.z; s3 += v.w;
    }
    const int c0 = (tid & 7) * 4;                   // channel group, invariant
    atomicAdd(&tot[c0 + 0], s0);                    // LDS atomics only (cheap)
    atomicAdd(&tot[c0 + 1], s1);
    atomicAdd(&tot[c0 + 2], s2);
    atomicAdd(&tot[c0 + 3], s3);
    __syncthreads();
    if (tid < CH) partials[(size_t)blockIdx.x * CH + tid] = tot[tid];  // own line
}

// ---- K2: one block reduces partials + edges -> scalar s ----
__global__ __launch_bounds__(256) void scalar2_kernel(const float* __restrict__ x,
                                                      const float* __restrict__ Wconv,
                                                      const float* __restrict__ bconv,
                                                      const float* __restrict__ Wdef,
                                                      const float* __restrict__ partials,
                                                      float* __restrict__ ws) {
    __shared__ float ltot[CH];
    __shared__ float hb[4][CH], tb[4][CH];
    __shared__ float partial[256];
    const int tid = threadIdx.x;
    if (tid < CH) ltot[tid] = 0.f;
    __syncthreads();

    // reduce 2048x32 partials: 16384 float4, coalesced, channel-aligned
    {
        const float4* p4 = (const float4*)partials;
        float s0 = 0.f, s1 = 0.f, s2 = 0.f, s3 = 0.f;
#pragma unroll 8
        for (int i = 0; i < 64; ++i) {
            float4 v = p4[i * 256 + tid];
            s0 += v.x; s1 += v.y; s2 += v.z; s3 += v.w;
        }
        int c0 = (tid & 7) * 4;
        atomicAdd(&ltot[c0 + 0], s0);
        atomicAdd(&ltot[c0 + 1], s1);
        atomicAdd(&ltot[c0 + 2], s2);
        atomicAdd(&ltot[c0 + 3], s3);
    }
    // head/tail edge sums (16 independent loads per thread)
    {
        int j = tid >> 5, c = tid & 31;             // j in 0..7
        int row = (j < 4) ? j : (T - 8 + j);
        float e = 0.f;
        for (int bb = 0; bb < NB; ++bb)
            e += x[((size_t)bb * T + row) * CH + c];
        if (j < 4) hb[j][c] = e; else tb[j - 4][c] = e;
    }
    __syncthreads();

    float term = 0.f;
    if (tid < KS * CH) {
        int k = tid >> 5, c = tid & 31;
        float wf = 0.f;
        const float* wp = &Wconv[(size_t)tid * NF];
        for (int f = 0; f < NF; ++f) wf += wp[f];
        float S = ltot[c];
        for (int jj = 0; jj < k; ++jj) S -= hb[jj][c];
        for (int jj = k; jj < 4; ++jj) S -= tb[jj][c];
        term = wf * S;
    }
    partial[tid] = term;
    __syncthreads();
    for (int off = 128; off > 0; off >>= 1) {
        if (tid < off) partial[tid] += partial[tid + off];
        __syncthreads();
    }
    if (tid == 0) {
        float sum_b = 0.f;
        for (int f = 0; f < NF; ++f) sum_b += bconv[f];
        float mean_off = partial[0] / (float)((size_t)NB * TOUT * NF) + sum_b / (float)NF;
        float s = 0.f;
        for (int k = 0; k < KS; ++k) {
            float pn = mean_off + (float)(k - 2);
            s += Wdef[k] * fmaxf(0.f, 1.f - fabsf(pn));
        }
        ws[CH] = s;
    }
}

// ---- K3: conv via f16 MFMA (round-1 proven, unchanged) ----
__global__ __launch_bounds__(256) void conv_kernel(const float* __restrict__ x,
                                                   const float* __restrict__ Wconv,
                                                   const float* __restrict__ bconv,
                                                   const float* __restrict__ ws,
                                                   float* __restrict__ out) {
    __shared__ _Float16 A[(BM + 4) * 40];
    __shared__ _Float16 Wt[KS * CH * 40];

    int tid = threadIdx.x;
    int b   = blockIdx.y;
    int t0  = blockIdx.x * BM;

    const int AROWS = BM + 4;
    {
        int c0 = (tid & 7) * 4;
        for (int r = (tid >> 3); r < AROWS; r += 32) {
            int t = t0 + r;
            float4 v = make_float4(0.f, 0.f, 0.f, 0.f);
            if (t < T) v = *(const float4*)&x[((size_t)b * T + t) * CH + c0];
            *(f16x4*)&A[r * 40 + c0] = cvt4(v);
        }
    }
    if (tid < KS * CH) {
        int k = tid >> 5, c = tid & 31;
        const float* wp = &Wconv[(size_t)tid * NF];
        for (int f = 0; f < NF; ++f)
            Wt[(k * CH + f) * 40 + c] = (_Float16)wp[f];
    }
    __syncthreads();

    int lane = tid & 63;
    int wave = tid >> 6;
    int rowbase = wave * 32;
    int lrow = lane & 15;
    int kgrp = lane >> 4;

    f32x4 acc00 = {}, acc01 = {}, acc10 = {}, acc11 = {};
#pragma unroll
    for (int kk = 0; kk < KS; ++kk) {
        f16x8 a0 = *(const f16x8*)&A[(rowbase + lrow + kk) * 40 + kgrp * 8];
        f16x8 a1 = *(const f16x8*)&A[(rowbase + 16 + lrow + kk) * 40 + kgrp * 8];
        f16x8 b0 = *(const f16x8*)&Wt[(kk * CH + lrow) * 40 + kgrp * 8];
        f16x8 b1 = *(const f16x8*)&Wt[(kk * CH + 16 + lrow) * 40 + kgrp * 8];
        acc00 = __builtin_amdgcn_mfma_f32_16x16x32_f16(a0, b0, acc00, 0, 0, 0);
        acc01 = __builtin_amdgcn_mfma_f32_16x16x32_f16(a0, b1, acc01, 0, 0, 0);
        acc10 = __builtin_amdgcn_mfma_f32_16x16x32_f16(a1, b0, acc10, 0, 0, 0);
        acc11 = __builtin_amdgcn_mfma_f32_16x16x32_f16(a1, b1, acc11, 0, 0, 0);
    }

    float sv  = ws[CH];
    int col0  = lane & 15;
    float bc0 = bconv[col0], bc1 = bconv[col0 + 16];
    int rbase = rowbase + ((lane >> 4) << 2);
#pragma unroll
    for (int reg = 0; reg < 4; ++reg) {
        int t = t0 + rbase + reg;
        if (t < TOUT) {
            float* o = &out[((size_t)b * TOUT + t) * NF];
            o[col0]      = sv * acc00[reg] + bc0;
            o[col0 + 16] = sv * acc01[reg] + bc1;
        }
        int t1 = t + 16;
        if (t1 < TOUT) {
            float* o = &out[((size_t)b * TOUT + t1) * NF];
            o[col0]      = sv * acc10[reg] + bc0;
            o[col0 + 16] = sv * acc11[reg] + bc1;
        }
    }
}

extern "C" void kernel_launch(void* const* d_in, const int* in_sizes, int n_in,
                              void* d_out, int out_size, void* d_ws, size_t ws_size,
                              hipStream_t stream) {
    const float* x     = (const float*)d_in[0];
    const float* Wconv = (const float*)d_in[1];
    const float* bconv = (const float*)d_in[2];
    const float* Wdef  = (const float*)d_in[3];
    float* out      = (float*)d_out;
    float* ws       = (float*)d_ws;
    float* partials = ws + 64;    // byte offset 256; 2048*32 floats = 256 KB

    chsum3_kernel<<<dim3(NCHB), dim3(256), 0, stream>>>(x, partials);
    scalar2_kernel<<<dim3(1), dim3(256), 0, stream>>>(x, Wconv, bconv, Wdef, partials, ws);
    dim3 grid((TOUT + BM - 1) / BM, NB);
    conv_kernel<<<grid, dim3(256), 0, stream>>>(x, Wconv, bconv, ws, out);
}